// Round 13
// baseline (308.459 us; speedup 1.0000x reference)
//
#include <hip/hip_runtime.h>
#include <cmath>

// NonLocalBlock: GN -> QKV(1x1) -> softmax(QK^T/sqrt(C))V -> proj -> +x
// B=16, C=512, H=W=32, N=1024, G=32 (16 ch/group), fp32 in/out.
//
// Round 12: attn occupancy 2->3 blocks/CU.
//   attn_mfma: alias S(f32) and P(bf16) buffers (union SPf; softmax loads all
//   16 scores to regs, extra __syncthreads, then overwrites with bf16 P).
//   LDS 58.9KB -> 48.9KB; __launch_bounds__(256,3). Arithmetic unchanged.
//   All other kernels identical to r11 (GEMMs validated this round: total 253us).

#define BB 16
#define CC 512
#define NN 1024
#define NG 32
#define CPG 16
#define EPSV 1e-6f
#define SCALE 0.044194173824159216f  // 1/sqrt(512)

typedef __attribute__((ext_vector_type(8))) short short8;
typedef __attribute__((ext_vector_type(16))) float f32x16;
typedef __attribute__((ext_vector_type(4))) float f32x4;

static __device__ __forceinline__ ushort f2bf(float f) {
  uint32_t x = __float_as_uint(f);
  uint32_t r = (x + 0x7fffu + ((x >> 16) & 1u)) >> 16;  // RNE
  return (ushort)r;
}
static __device__ __forceinline__ float bf2f(ushort u) {
  return __uint_as_float(((uint32_t)u) << 16);
}

// ---------------------------------------------------------------- gn stats
__global__ __launch_bounds__(256) void gn_stats_kernel(const float* __restrict__ x,
                                                       float* __restrict__ stats) {
  const int bg = blockIdx.x;
  const int t  = threadIdx.x;
  const float4* xp = (const float4*)(x + (size_t)bg * (CPG * NN));
  float s = 0.f, ss = 0.f;
  #pragma unroll
  for (int it = 0; it < (CPG * NN / 4) / 256; ++it) {
    float4 v = xp[it * 256 + t];
    s  += v.x + v.y + v.z + v.w;
    ss += v.x * v.x + v.y * v.y + v.z * v.z + v.w * v.w;
  }
  #pragma unroll
  for (int off = 32; off >= 1; off >>= 1) {
    s  += __shfl_down(s, off);
    ss += __shfl_down(ss, off);
  }
  __shared__ float red[4][2];
  if ((t & 63) == 0) { red[t >> 6][0] = s; red[t >> 6][1] = ss; }
  __syncthreads();
  if (t == 0) {
    s  = red[0][0] + red[1][0] + red[2][0] + red[3][0];
    ss = red[0][1] + red[1][1] + red[2][1] + red[3][1];
    const float inv  = 1.f / (float)(CPG * NN);
    const float mean = s * inv;
    const float var  = ss * inv - mean * mean;
    stats[bg * 2 + 0] = mean;
    stats[bg * 2 + 1] = rsqrtf(var + EPSV);
  }
}

// ------------------------------------------------- xn: normalize + transpose to [n][c] bf16
__global__ __launch_bounds__(256) void xn_kernel(const float* __restrict__ x,
                                                 const float* __restrict__ stats,
                                                 const float* __restrict__ gamma,
                                                 const float* __restrict__ beta,
                                                 ushort* __restrict__ xnbuf) {
  __shared__ ushort Tl[64][65];
  const int b  = blockIdx.z;
  const int n0 = blockIdx.x * 64;
  const int c0 = blockIdx.y * 64;
  const int t  = threadIdx.x;
  {
    const int cr = t >> 2, f4 = t & 3;     // 64 c-rows x 4 threads
    const int c  = c0 + cr;
    const float mean = stats[(b * NG + (c >> 4)) * 2 + 0];
    const float rstd = stats[(b * NG + (c >> 4)) * 2 + 1];
    const float ga = gamma[c], be = beta[c];
    const float4* src = (const float4*)(x + ((size_t)b * CC + c) * NN + n0) + f4 * 4;
    #pragma unroll
    for (int j = 0; j < 4; ++j) {
      const float4 v = src[j];
      const int nn = f4 * 16 + j * 4;
      Tl[cr][nn + 0] = f2bf((v.x - mean) * rstd * ga + be);
      Tl[cr][nn + 1] = f2bf((v.y - mean) * rstd * ga + be);
      Tl[cr][nn + 2] = f2bf((v.z - mean) * rstd * ga + be);
      Tl[cr][nn + 3] = f2bf((v.w - mean) * rstd * ga + be);
    }
  }
  __syncthreads();
  {
    const int nr = t >> 2, s = t & 3;      // 64 n-rows x 4 threads, 16 c each
    ushort* dst = xnbuf + ((size_t)b * NN + n0 + nr) * CC + c0 + s * 16;
    #pragma unroll
    for (int u = 0; u < 2; ++u) {
      short8 o;
      #pragma unroll
      for (int e = 0; e < 8; ++e) o[e] = (short)Tl[s * 16 + u * 8 + e][nr];
      *(short8*)(dst + u * 8) = o;
    }
  }
}

// ------------------------------------------------- weight fp32 -> bf16
__global__ __launch_bounds__(256) void wconv_kernel(const float* __restrict__ wq,
                                                    const float* __restrict__ wp,
                                                    ushort* __restrict__ wqb,
                                                    ushort* __restrict__ wpb) {
  const size_t idx = (size_t)blockIdx.x * 256 + threadIdx.x;
  const size_t e = idx * 8;
  const size_t total1 = (size_t)1536 * 512;
  const float* src;
  ushort* dst;
  size_t off;
  if (e < total1) { src = wq; dst = wqb; off = e; }
  else            { src = wp; dst = wpb; off = e - total1; }
  const float4 v0 = *(const float4*)(src + off);
  const float4 v1 = *(const float4*)(src + off + 4);
  short8 o;
  o[0] = (short)f2bf(v0.x); o[1] = (short)f2bf(v0.y);
  o[2] = (short)f2bf(v0.z); o[3] = (short)f2bf(v0.w);
  o[4] = (short)f2bf(v1.x); o[5] = (short)f2bf(v1.y);
  o[6] = (short)f2bf(v1.z); o[7] = (short)f2bf(v1.w);
  *(short8*)(dst + off) = o;
}

// ------------------------------------------------- bf16 MFMA GEMM (m97-style)
// C[128 m][128 o] = A[128 m][512] . W[128 o][512]^T ; BK=64, 8 K-steps.
// LDS tiles [128 rows][64 k] bf16; granule XOR swizzle g' = g ^ (row&7).
__device__ __forceinline__ void stage_tile64(const ushort* __restrict__ src,
                                             ushort* lds, int w, int lane) {
  #pragma unroll
  for (int i = 0; i < 4; ++i) {
    const int ii  = i * 4 + w;                    // 16 instrs per tile
    const int row = ii * 8 + (lane >> 3);
    const int sg  = (lane & 7) ^ (lane >> 3);     // inverse-swizzled source granule
    __builtin_amdgcn_global_load_lds(
        (const __attribute__((address_space(1))) void*)(src + (size_t)row * 512 + sg * 8),
        (__attribute__((address_space(3))) void*)(lds + ii * 512),
        16, 0, 0);
  }
}

template <int MODE>  // 0 = qkv (bf16 q/k/v-planes out), 1 = proj (+bias+residual fp32 out)
__global__ __launch_bounds__(256, 3) void gemm_mfma_kernel(const ushort* __restrict__ A,
                                                           const ushort* __restrict__ W,
                                                           const float* __restrict__ bias,
                                                           const float* __restrict__ xres,
                                                           ushort* __restrict__ qbuf,
                                                           ushort* __restrict__ kbuf,
                                                           ushort* __restrict__ vbuf,
                                                           float* __restrict__ out) {
  __shared__ ushort As[128 * 64];
  __shared__ ushort Bs[128 * 64];
  const int b  = blockIdx.z;
  const int m0 = blockIdx.x * 128;
  const int o0 = blockIdx.y * 128;
  const int t  = threadIdx.x;
  const int lane = t & 63;
  const int w  = t >> 6;
  const int wr = w >> 1, wc = w & 1;     // wave sub-tile (64x64)
  const int lf = lane & 15;              // frag row/col within 16
  const int qw = lane >> 4;              // k-group / C-row group

  const ushort* Ab = A + ((size_t)b * NN + m0) * CC;
  const ushort* Wb = W + (size_t)o0 * CC;

  f32x4 acc[4][4];
  #pragma unroll
  for (int mf = 0; mf < 4; ++mf)
    #pragma unroll
    for (int nf = 0; nf < 4; ++nf)
      #pragma unroll
      for (int r = 0; r < 4; ++r) acc[mf][nf][r] = 0.f;

  for (int k0 = 0; k0 < CC; k0 += 64) {
    __syncthreads();                      // protect previous tile's readers
    stage_tile64(Ab + k0, As, w, lane);
    stage_tile64(Wb + k0, Bs, w, lane);
    __syncthreads();                      // vmcnt drained by compiler
    #pragma unroll
    for (int kk = 0; kk < 2; ++kk) {
      short8 af[4], bf[4];
      #pragma unroll
      for (int mf = 0; mf < 4; ++mf) {
        const int row = wr * 64 + mf * 16 + lf;
        const int g   = ((kk << 2) | qw) ^ (row & 7);
        af[mf] = *(const short8*)((const char*)As + row * 128 + g * 16);
      }
      #pragma unroll
      for (int nf = 0; nf < 4; ++nf) {
        const int row = wc * 64 + nf * 16 + lf;
        const int g   = ((kk << 2) | qw) ^ (row & 7);
        bf[nf] = *(const short8*)((const char*)Bs + row * 128 + g * 16);
      }
      #pragma unroll
      for (int mf = 0; mf < 4; ++mf)
        #pragma unroll
        for (int nf = 0; nf < 4; ++nf)
          acc[mf][nf] = __builtin_amdgcn_mfma_f32_16x16x32_bf16(af[mf], bf[nf], acc[mf][nf], 0, 0, 0);
    }
  }

  // epilogue: C col = o0+wc*64+nf*16+lf, row = m0+wr*64+mf*16+qw*4+r
  float bv[4];
  #pragma unroll
  for (int nf = 0; nf < 4; ++nf) bv[nf] = bias[o0 + wc * 64 + nf * 16 + lf];

  if (MODE == 0) {
    if (o0 < 1024) {  // q or k plane [n][512], q pre-scaled
      ushort* plane = (o0 < 512 ? qbuf : kbuf) + (size_t)b * NN * CC;
      const int oo = (o0 < 512 ? o0 : o0 - 512) + wc * 64;
      const float sc = (o0 < 512) ? SCALE : 1.f;
      #pragma unroll
      for (int mf = 0; mf < 4; ++mf)
        #pragma unroll
        for (int r = 0; r < 4; ++r) {
          const int n = m0 + wr * 64 + mf * 16 + qw * 4 + r;
          #pragma unroll
          for (int nf = 0; nf < 4; ++nf)
            plane[(size_t)n * CC + oo + nf * 16 + lf] = f2bf((acc[mf][nf][r] + bv[nf]) * sc);
        }
    } else {          // v plane transposed [d][n]
      ushort* vb = vbuf + (size_t)b * CC * NN;
      #pragma unroll
      for (int nf = 0; nf < 4; ++nf) {
        const int d = o0 - 1024 + wc * 64 + nf * 16 + lf;
        #pragma unroll
        for (int mf = 0; mf < 4; ++mf)
          #pragma unroll
          for (int r = 0; r < 4; ++r) {
            const int n = m0 + wr * 64 + mf * 16 + qw * 4 + r;
            vb[(size_t)d * NN + n] = f2bf(acc[mf][nf][r] + bv[nf]);
          }
      }
    }
  } else {            // proj: out[oc][n] = acc + bias + x
    const float* xb = xres + (size_t)b * CC * NN;
    float* ob = out + (size_t)b * CC * NN;
    #pragma unroll
    for (int nf = 0; nf < 4; ++nf) {
      const int oc = o0 + wc * 64 + nf * 16 + lf;
      #pragma unroll
      for (int mf = 0; mf < 4; ++mf)
        #pragma unroll
        for (int r = 0; r < 4; ++r) {
          const int n = m0 + wr * 64 + mf * 16 + qw * 4 + r;
          const size_t idx = (size_t)oc * NN + n;
          ob[idx] = acc[mf][nf][r] + bv[nf] + xb[idx];
        }
    }
  }
}

// ------------------------------------------------------------- flash attention (MFMA)
// r12 change: S(f32) and P(bf16) share one LDS buffer (SPf). Softmax loads all
// 16 scores into registers, then a barrier, then overwrites with bf16 P.
// Barrier-ordering audit: every SPf(write)<->Pl(read) pair crosses >=1 barrier:
//   S-store -> softmax read: post-S-store barrier. softmax read -> P write: NEW barrier.
//   P write -> PV read: post-softmax barrier. PV read (k0) -> S-store (k0+1):
//   cc-loop barriers. LDS 48.9KB -> 3 blocks/CU.
__device__ __forceinline__ void stage_chunk(const ushort* __restrict__ src, int stride,
                                            ushort* kv, int w, int lane) {
  #pragma unroll
  for (int i = 0; i < 8; ++i) {
    const int base = (i * 4 + w) * 1024;                 // bytes, wave-uniform
    const int r    = (base >> 8) + (lane >> 4);          // row 0..127
    const int sx   = ((lane & 15) << 4) ^ ((r & 15) << 4);
    __builtin_amdgcn_global_load_lds(
        (const __attribute__((address_space(1))) void*)(src + (size_t)r * stride + (sx >> 1)),
        (__attribute__((address_space(3))) void*)(kv + (base >> 1)),
        16, 0, 0);
  }
}

__global__ __launch_bounds__(256, 3) void attn_mfma_kernel(const ushort* __restrict__ qb,
                                                           const ushort* __restrict__ kb,
                                                           const ushort* __restrict__ vb,
                                                           ushort* __restrict__ yb) {
  __shared__ ushort KV[128 * 128];   // 32KB chunk
  __shared__ float  SPf[32 * 132];   // 16.5KB: S scores f32, aliased as P bf16 [32][136]
  __shared__ float  m_s[32], l_s[32], c_s[32];
  ushort* Pl = (ushort*)SPf;

  const int orig = blockIdx.x + blockIdx.y * gridDim.x;   // 0..511
  const int wg   = (orig & 7) * 64 + (orig >> 3);
  const int b    = wg >> 5;
  const int q0   = (wg & 31) * 32;
  const int t    = threadIdx.x;
  const int lane = t & 63;
  const int w    = t >> 6;
  const int lr   = lane & 31;
  const int lh   = lane >> 5;

  const ushort* qbb = qb + (size_t)b * NN * CC;
  const ushort* kbb = kb + (size_t)b * NN * CC;
  const ushort* vbb = vb + (size_t)b * CC * NN;
  ushort* ybb = yb + (size_t)b * NN * CC;

  if (t < 32) { m_s[t] = -INFINITY; l_s[t] = 0.f; }

  short8 qf[32];
  #pragma unroll
  for (int f = 0; f < 32; ++f)
    qf[f] = *(const short8*)&qbb[(size_t)(q0 + lr) * CC + f * 16 + lh * 8];

  f32x16 Ov[4];
  #pragma unroll
  for (int ci = 0; ci < 4; ++ci)
    #pragma unroll
    for (int rg = 0; rg < 16; ++rg) Ov[ci][rg] = 0.f;

  for (int k0 = 0; k0 < NN; k0 += 128) {
    f32x16 S;
    #pragma unroll
    for (int rg = 0; rg < 16; ++rg) S[rg] = 0.f;
    #pragma unroll
    for (int cc = 0; cc < 4; ++cc) {
      __syncthreads();                    // protect prev KV (and Pl) readers
      stage_chunk(kbb + (size_t)k0 * CC + cc * 128, CC, KV, w, lane);
      __syncthreads();                    // vmcnt drained
      const int krow = w * 32 + lr;
      #pragma unroll
      for (int cs = 0; cs < 8; ++cs) {
        const int boff = (krow << 8) + ((((cs * 16 + lh * 8) << 1)) ^ ((krow & 15) << 4));
        short8 kf = *(const short8*)((const char*)KV + boff);
        S = __builtin_amdgcn_mfma_f32_32x32x16_bf16(qf[cc * 8 + cs], kf, S, 0, 0, 0);
      }
    }
    // ---- S -> LDS (C layout: col=lane&31, row=(rg&3)+8*(rg>>2)+4*lh) ----
    #pragma unroll
    for (int rg = 0; rg < 16; ++rg) {
      const int r = (rg & 3) + 8 * (rg >> 2) + 4 * lh;
      SPf[r * 132 + w * 32 + lr] = S[rg];
    }
    __syncthreads();
    // ---- online softmax: row = t>>3, 8 threads x 16 cols each ----
    {
      const int row = t >> 3, seg = t & 7;
      float v[16];
      float mx = -INFINITY;
      #pragma unroll
      for (int u = 0; u < 16; ++u) { v[u] = SPf[row * 132 + seg * 16 + u]; mx = fmaxf(mx, v[u]); }
      mx = fmaxf(mx, __shfl_xor(mx, 1));
      mx = fmaxf(mx, __shfl_xor(mx, 2));
      mx = fmaxf(mx, __shfl_xor(mx, 4));
      __syncthreads();                    // ALL S reads complete before P overwrites (alias)
      const float mo = m_s[row];
      const float mn = fmaxf(mo, mx);
      const float corr = __expf(mo - mn);
      float ps = 0.f;
      #pragma unroll
      for (int u = 0; u < 16; ++u) {
        const float p = __expf(v[u] - mn);
        ps += p;
        Pl[row * 136 + seg * 16 + u] = f2bf(p);
      }
      ps += __shfl_xor(ps, 1);
      ps += __shfl_xor(ps, 2);
      ps += __shfl_xor(ps, 4);
      if (seg == 0) {
        c_s[row] = corr;
        m_s[row] = mn;
        l_s[row] = l_s[row] * corr + ps;
      }
    }
    __syncthreads();
    // ---- rescale O ----
    float cr[16];
    #pragma unroll
    for (int rg = 0; rg < 16; ++rg) cr[rg] = c_s[(rg & 3) + 8 * (rg >> 2) + 4 * lh];
    #pragma unroll
    for (int ci = 0; ci < 4; ++ci)
      #pragma unroll
      for (int rg = 0; rg < 16; ++rg) Ov[ci][rg] *= cr[rg];
    // ---- O += P V over 4 d-chunks of 128 ----
    #pragma unroll
    for (int ci = 0; ci < 4; ++ci) {
      __syncthreads();
      stage_chunk(vbb + (size_t)(ci * 128) * NN + k0, NN, KV, w, lane);
      __syncthreads();
      const int vrow = w * 32 + lr;
      #pragma unroll
      for (int ks = 0; ks < 8; ++ks) {
        short8 pf = *(const short8*)((const char*)Pl + lr * 272 + ks * 32 + lh * 16);
        const int boff = (vrow << 8) + ((((ks * 16 + lh * 8) << 1)) ^ ((vrow & 15) << 4));
        short8 vf = *(const short8*)((const char*)KV + boff);
        Ov[ci] = __builtin_amdgcn_mfma_f32_32x32x16_bf16(pf, vf, Ov[ci], 0, 0, 0);
      }
    }
  }

  float invl[16];
  #pragma unroll
  for (int rg = 0; rg < 16; ++rg) invl[rg] = 1.f / l_s[(rg & 3) + 8 * (rg >> 2) + 4 * lh];
  #pragma unroll
  for (int ci = 0; ci < 4; ++ci)
    #pragma unroll
    for (int rg = 0; rg < 16; ++rg) {
      const int r = (rg & 3) + 8 * (rg >> 2) + 4 * lh;
      const int d = ci * 128 + w * 32 + lr;
      ybb[(size_t)(q0 + r) * CC + d] = f2bf(Ov[ci][rg] * invl[rg]);
    }
}

// ---------------------------------------------------------------- launch
extern "C" void kernel_launch(void* const* d_in, const int* in_sizes, int n_in,
                              void* d_out, int out_size, void* d_ws, size_t ws_size,
                              hipStream_t stream) {
  const float* x      = (const float*)d_in[0];
  const float* gamma  = (const float*)d_in[1];
  const float* beta   = (const float*)d_in[2];
  const float* w_qkv  = (const float*)d_in[3];
  const float* b_qkv  = (const float*)d_in[4];
  const float* w_proj = (const float*)d_in[5];
  const float* b_proj = (const float*)d_in[6];
  float* out = (float*)d_out;

  const size_t PL = (size_t)BB * NN * CC;          // 8M ushorts per plane
  float*  stats = (float*)d_ws;                                    // 4KB
  ushort* xnbuf = (ushort*)((char*)d_ws + 4096);
  ushort* qbuf  = xnbuf + PL;
  ushort* kbuf  = qbuf + PL;
  ushort* vbuf  = kbuf + PL;
  ushort* ybuf  = vbuf + PL;
  ushort* wqb   = ybuf + PL;                        // [1536][512] bf16
  ushort* wpb   = wqb + (size_t)1536 * 512;         // [512][512] bf16

  hipLaunchKernelGGL(gn_stats_kernel, dim3(BB * NG), dim3(256), 0, stream, x, stats);
  hipLaunchKernelGGL(xn_kernel, dim3(NN / 64, CC / 64, BB), dim3(256), 0, stream,
                     x, stats, gamma, beta, xnbuf);
  hipLaunchKernelGGL(wconv_kernel, dim3(512), dim3(256), 0, stream,
                     w_qkv, w_proj, wqb, wpb);
  hipLaunchKernelGGL((gemm_mfma_kernel<0>), dim3(NN / 128, 1536 / 128, BB), dim3(256), 0, stream,
                     xnbuf, wqb, b_qkv, nullptr, qbuf, kbuf, vbuf, nullptr);
  hipLaunchKernelGGL(attn_mfma_kernel, dim3(NN / 32, BB), dim3(256), 0, stream,
                     qbuf, kbuf, vbuf, ybuf);
  hipLaunchKernelGGL((gemm_mfma_kernel<1>), dim3(NN / 128, CC / 128, BB), dim3(256), 0, stream,
                     ybuf, wpb, b_proj, x, nullptr, nullptr, nullptr, out);
}